// Round 3
// baseline (626.684 us; speedup 1.0000x reference)
//
#include <hip/hip_runtime.h>

#define NC 5
#define DICE_EPS 1e-7f

typedef unsigned long long u64;
typedef unsigned int u32;

// Workspace layout (u32 cnt[256], memset to 0 each launch):
// cnt[c*16]        : den1[c] = count(pred == c)      (own cacheline each)
// cnt[(5+c)*16]    : den2[c] = count(mask == c)
// cnt[(10+c)*16]   : num[c]  = count(pred == c && mask == c)
// cnt[240]         : block-completion ticket

__device__ __forceinline__ void accum4(float4 pf, int4 mv,
                                       u64& A1, u64& A2, u64& AN)
{
    // Packed 8-bit-per-class counters: class c in bits [8c, 8c+8).
    // Bits [40,48) are a trash bin for "prediction != label".
    int p0 = (int)pf.x, p1 = (int)pf.y, p2 = (int)pf.z, p3 = (int)pf.w;
    int s0 = p0 << 3, s1 = p1 << 3, s2 = p2 << 3, s3 = p3 << 3;
    A1 += (1ull << s0) + (1ull << s1) + (1ull << s2) + (1ull << s3);
    A2 += (1ull << (mv.x << 3)) + (1ull << (mv.y << 3)) +
          (1ull << (mv.z << 3)) + (1ull << (mv.w << 3));
    AN += (1ull << (p0 == mv.x ? s0 : 40)) +
          (1ull << (p1 == mv.y ? s1 : 40)) +
          (1ull << (p2 == mv.z ? s2 : 40)) +
          (1ull << (p3 == mv.w ? s3 : 40));
}

#define FLUSH()                                                         \
    do {                                                                \
        _Pragma("unroll")                                               \
        for (int c = 0; c < NC; ++c) {                                  \
            den1[c] += (u32)(A1 >> (8 * c)) & 0xFF;                     \
            den2[c] += (u32)(A2 >> (8 * c)) & 0xFF;                     \
            num [c] += (u32)(AN >> (8 * c)) & 0xFF;                     \
        }                                                               \
        A1 = 0; A2 = 0; AN = 0;                                         \
    } while (0)

__global__ __launch_bounds__(256) void dice_hist_kernel(
    const float* __restrict__ pred_f, const int* __restrict__ mask,
    u32* __restrict__ cnt, float* __restrict__ out, int n, int nblocks)
{
    u32 den1[NC] = {0, 0, 0, 0, 0};
    u32 den2[NC] = {0, 0, 0, 0, 0};
    u32 num [NC] = {0, 0, 0, 0, 0};

    const int nt  = gridDim.x * blockDim.x;
    const int tid = blockIdx.x * blockDim.x + threadIdx.x;
    const int n4  = n >> 2;

    const float4* __restrict__ p4 = (const float4*)pred_f;
    const int4*   __restrict__ m4 = (const int4*)mask;

    u64 A1 = 0, A2 = 0, AN = 0;
    int cin = 0;   // elements accumulated since last flush (max field: 240+16=256? no: flush at >=240 keeps <=240+... see below)

    int i = tid;
    // Main loop: unroll-by-4 grid stride — 8 independent 16B loads in flight.
    for (; i + 3 * nt < n4; i += 4 * nt) {
        float4 a0 = p4[i];
        float4 a1 = p4[i + nt];
        float4 a2 = p4[i + 2 * nt];
        float4 a3 = p4[i + 3 * nt];
        int4   b0 = m4[i];
        int4   b1 = m4[i + nt];
        int4   b2 = m4[i + 2 * nt];
        int4   b3 = m4[i + 3 * nt];
        accum4(a0, b0, A1, A2, AN);
        accum4(a1, b1, A1, A2, AN);
        accum4(a2, b2, A1, A2, AN);
        accum4(a3, b3, A1, A2, AN);
        cin += 16;
        if (cin >= 224) { FLUSH(); cin = 0; }   // field max 224+16=240 < 256
    }
    for (; i < n4; i += nt) {
        accum4(p4[i], m4[i], A1, A2, AN);
        cin += 4;
        if (cin >= 224) { FLUSH(); cin = 0; }
    }
    FLUSH();

    // scalar tail (n % 4 != 0; not hit for this problem's sizes)
    for (int j = (n4 << 2) + tid; j < n; j += nt) {
        int p = (int)pred_f[j];
        int m = mask[j];
        #pragma unroll
        for (int c = 0; c < NC; ++c) {
            u32 a = (p == c), b = (m == c);
            den1[c] += a;
            den2[c] += b;
            num [c] += a & b;
        }
    }

    // wave-level butterfly reduce (wave = 64 lanes)
    #pragma unroll
    for (int c = 0; c < NC; ++c) {
        #pragma unroll
        for (int off = 32; off > 0; off >>= 1) {
            den1[c] += __shfl_xor(den1[c], off, 64);
            den2[c] += __shfl_xor(den2[c], off, 64);
            num [c] += __shfl_xor(num [c], off, 64);
        }
    }

    __shared__ u32 s_cnt[3 * NC];
    if (threadIdx.x < 3 * NC) s_cnt[threadIdx.x] = 0;
    __syncthreads();

    const int lane = threadIdx.x & 63;
    if (lane == 0) {
        #pragma unroll
        for (int c = 0; c < NC; ++c) {
            atomicAdd(&s_cnt[c],          den1[c]);
            atomicAdd(&s_cnt[NC + c],     den2[c]);
            atomicAdd(&s_cnt[2 * NC + c], num [c]);
        }
    }
    __syncthreads();

    if (threadIdx.x < 3 * NC) {
        atomicAdd(&cnt[threadIdx.x * 16], s_cnt[threadIdx.x]);
    }
    __threadfence();
    __syncthreads();   // all global atomics of this block performed

    // Last-block-done epilogue: fused dice computation.
    __shared__ u32 ticket;
    if (threadIdx.x == 0) ticket = atomicAdd(&cnt[240], 1u);
    __syncthreads();
    if (ticket == (u32)(nblocks - 1) && threadIdx.x == 0) {
        float s = 0.0f;
        #pragma unroll
        for (int c = 0; c < NC; ++c) {
            float d1 = (float)atomicAdd(&cnt[c * 16], 0u);
            float d2 = (float)atomicAdd(&cnt[(NC + c) * 16], 0u);
            float nm = (float)atomicAdd(&cnt[(2 * NC + c) * 16], 0u);
            s += 2.0f * ((nm + DICE_EPS) / (d1 + d2 + DICE_EPS));
        }
        out[0] = s / (float)NC;
    }
}

extern "C" void kernel_launch(void* const* d_in, const int* in_sizes, int n_in,
                              void* d_out, int out_size, void* d_ws, size_t ws_size,
                              hipStream_t stream) {
    const float* pred = (const float*)d_in[0];   // "output": float32 labels
    const int*   mask = (const int*)d_in[1];     // "mask": int32 labels
    const int n = in_sizes[0];                   // 128*512*512 = 33,554,432

    u32* cnt = (u32*)d_ws;
    hipMemsetAsync(d_ws, 0, 256 * sizeof(u32), stream);

    const int threads = 256;
    const int blocks = 2048;   // 8 blocks/CU; 16 vec4-iters/thread (4 unrolled groups)
    dice_hist_kernel<<<blocks, threads, 0, stream>>>(pred, mask, cnt,
                                                     (float*)d_out, n, blocks);
}

// Round 4
// 282.358 us; speedup vs baseline: 2.2195x; 2.2195x over previous
//
#include <hip/hip_runtime.h>

#define NC 5
#define DICE_EPS 1e-7f

typedef unsigned long long u64;
typedef unsigned int u32;

// Workspace layout (u32 cnt[256], memset to 0 each launch):
// cnt[c*16]        : den1[c] = count(pred == c)      (own cacheline each)
// cnt[(5+c)*16]    : den2[c] = count(mask == c)
// cnt[(10+c)*16]   : num[c]  = count(pred == c && mask == c)

#define BLOCKS 2048
#define CHUNK  4096   // float4 elements per block (64 KB per array per block)

__device__ __forceinline__ void accum4(float4 pf, int4 mv,
                                       u64& A1, u64& A2, u64& AN)
{
    // Packed 8-bit-per-class counters: class c in bits [8c, 8c+8).
    // Bits [40,48) are a trash bin for "prediction != label".
    int p0 = (int)pf.x, p1 = (int)pf.y, p2 = (int)pf.z, p3 = (int)pf.w;
    int s0 = p0 << 3, s1 = p1 << 3, s2 = p2 << 3, s3 = p3 << 3;
    A1 += (1ull << s0) + (1ull << s1) + (1ull << s2) + (1ull << s3);
    A2 += (1ull << (mv.x << 3)) + (1ull << (mv.y << 3)) +
          (1ull << (mv.z << 3)) + (1ull << (mv.w << 3));
    AN += (1ull << (p0 == mv.x ? s0 : 40)) +
          (1ull << (p1 == mv.y ? s1 : 40)) +
          (1ull << (p2 == mv.z ? s2 : 40)) +
          (1ull << (p3 == mv.w ? s3 : 40));
}

#define FLUSH()                                                         \
    do {                                                                \
        _Pragma("unroll")                                               \
        for (int c = 0; c < NC; ++c) {                                  \
            den1[c] += (u32)(A1 >> (8 * c)) & 0xFF;                     \
            den2[c] += (u32)(A2 >> (8 * c)) & 0xFF;                     \
            num [c] += (u32)(AN >> (8 * c)) & 0xFF;                     \
        }                                                               \
        A1 = 0; A2 = 0; AN = 0;                                         \
    } while (0)

__global__ __launch_bounds__(256) void dice_hist_kernel(
    const float* __restrict__ pred_f, const int* __restrict__ mask,
    u32* __restrict__ cnt, int n)
{
    u32 den1[NC] = {0, 0, 0, 0, 0};
    u32 den2[NC] = {0, 0, 0, 0, 0};
    u32 num [NC] = {0, 0, 0, 0, 0};

    const int tid = threadIdx.x;
    const int n4  = n >> 2;

    const float4* __restrict__ p4 = (const float4*)pred_f;
    const int4*   __restrict__ m4 = (const int4*)mask;

    u64 A1 = 0, A2 = 0, AN = 0;

    if (n4 == (int)gridDim.x * CHUNK) {
        // Fast path: block-contiguous chunk, clean 16-iter loop.
        // Per-field max = 16 iters * 4 elems = 64 < 256: one flush at end.
        const int base = blockIdx.x * CHUNK + tid;
        #pragma unroll 4
        for (int k = 0; k < CHUNK / 256; ++k) {
            int i = base + k * 256;
            accum4(p4[i], m4[i], A1, A2, AN);
        }
        FLUSH();
    } else {
        // Generic path: grid-stride with periodic flush.
        const int nt = gridDim.x * blockDim.x;
        int i = blockIdx.x * blockDim.x + tid;
        int cin = 0;
        for (; i < n4; i += nt) {
            accum4(p4[i], m4[i], A1, A2, AN);
            cin += 4;
            if (cin >= 224) { FLUSH(); cin = 0; }
        }
        FLUSH();
        for (int j = (n4 << 2) + blockIdx.x * blockDim.x + tid; j < n; j += nt) {
            int p = (int)pred_f[j];
            int m = mask[j];
            #pragma unroll
            for (int c = 0; c < NC; ++c) {
                u32 a = (p == c), b = (m == c);
                den1[c] += a;
                den2[c] += b;
                num [c] += a & b;
            }
        }
    }

    // wave-level butterfly reduce (wave = 64 lanes)
    #pragma unroll
    for (int c = 0; c < NC; ++c) {
        #pragma unroll
        for (int off = 32; off > 0; off >>= 1) {
            den1[c] += __shfl_xor(den1[c], off, 64);
            den2[c] += __shfl_xor(den2[c], off, 64);
            num [c] += __shfl_xor(num [c], off, 64);
        }
    }

    __shared__ u32 s_cnt[3 * NC];
    if (tid < 3 * NC) s_cnt[tid] = 0;
    __syncthreads();

    if ((tid & 63) == 0) {
        #pragma unroll
        for (int c = 0; c < NC; ++c) {
            atomicAdd(&s_cnt[c],          den1[c]);
            atomicAdd(&s_cnt[NC + c],     den2[c]);
            atomicAdd(&s_cnt[2 * NC + c], num [c]);
        }
    }
    __syncthreads();

    if (tid < 3 * NC) {
        atomicAdd(&cnt[tid * 16], s_cnt[tid]);
    }
}

__global__ void dice_final_kernel(const u32* __restrict__ cnt,
                                  float* __restrict__ out)
{
    if (blockIdx.x == 0 && threadIdx.x == 0) {
        float s = 0.0f;
        #pragma unroll
        for (int c = 0; c < NC; ++c) {
            float d1 = (float)cnt[c * 16];
            float d2 = (float)cnt[(NC + c) * 16];
            float nm = (float)cnt[(2 * NC + c) * 16];
            s += 2.0f * ((nm + DICE_EPS) / (d1 + d2 + DICE_EPS));
        }
        out[0] = s / (float)NC;
    }
}

extern "C" void kernel_launch(void* const* d_in, const int* in_sizes, int n_in,
                              void* d_out, int out_size, void* d_ws, size_t ws_size,
                              hipStream_t stream) {
    const float* pred = (const float*)d_in[0];   // "output": float32 labels
    const int*   mask = (const int*)d_in[1];     // "mask": int32 labels
    const int n = in_sizes[0];                   // 128*512*512 = 33,554,432

    u32* cnt = (u32*)d_ws;
    hipMemsetAsync(d_ws, 0, 256 * sizeof(u32), stream);

    dice_hist_kernel<<<BLOCKS, 256, 0, stream>>>(pred, mask, cnt, n);
    dice_final_kernel<<<1, 64, 0, stream>>>(cnt, (float*)d_out);
}

// Round 5
// 254.250 us; speedup vs baseline: 2.4648x; 1.1106x over previous
//
#include <hip/hip_runtime.h>

#define NC 5
#define DICE_EPS 1e-7f

typedef unsigned long long u64;
typedef unsigned int u32;
typedef float v4f __attribute__((ext_vector_type(4)));
typedef int   v4i __attribute__((ext_vector_type(4)));

// Workspace layout (u32 cnt[256], memset to 0 each launch):
// cnt[c*16]        : den1[c] = count(pred == c)      (own cacheline each)
// cnt[(5+c)*16]    : den2[c] = count(mask == c)
// cnt[(10+c)*16]   : num[c]  = count(pred == c && mask == c)

#define BLOCKS 1024
#define GROUPS 8   // unroll groups per wave; 1024 blk * 64 waves... see geometry check

__device__ __forceinline__ void accum4(v4f pf, v4i mv,
                                       u64& A1, u64& A2, u64& AN)
{
    // Packed 8-bit-per-class counters: class c in bits [8c, 8c+8).
    // Bits [40,48) are a trash bin for "prediction != label".
    int p0 = (int)pf.x, p1 = (int)pf.y, p2 = (int)pf.z, p3 = (int)pf.w;
    int s0 = p0 << 3, s1 = p1 << 3, s2 = p2 << 3, s3 = p3 << 3;
    A1 += (1ull << s0) + (1ull << s1) + (1ull << s2) + (1ull << s3);
    A2 += (1ull << (mv.x << 3)) + (1ull << (mv.y << 3)) +
          (1ull << (mv.z << 3)) + (1ull << (mv.w << 3));
    AN += (1ull << (p0 == mv.x ? s0 : 40)) +
          (1ull << (p1 == mv.y ? s1 : 40)) +
          (1ull << (p2 == mv.z ? s2 : 40)) +
          (1ull << (p3 == mv.w ? s3 : 40));
}

#define FLUSH()                                                         \
    do {                                                                \
        _Pragma("unroll")                                               \
        for (int c = 0; c < NC; ++c) {                                  \
            den1[c] += (u32)(A1 >> (8 * c)) & 0xFF;                     \
            den2[c] += (u32)(A2 >> (8 * c)) & 0xFF;                     \
            num [c] += (u32)(AN >> (8 * c)) & 0xFF;                     \
        }                                                               \
        A1 = 0; A2 = 0; AN = 0;                                         \
    } while (0)

__global__ __launch_bounds__(256) void dice_hist_kernel(
    const float* __restrict__ pred_f, const int* __restrict__ mask,
    u32* __restrict__ cnt, int n)
{
    u32 den1[NC] = {0, 0, 0, 0, 0};
    u32 den2[NC] = {0, 0, 0, 0, 0};
    u32 num [NC] = {0, 0, 0, 0, 0};

    const int tid = threadIdx.x;
    const int n4  = n >> 2;

    const v4f* __restrict__ p4 = (const v4f*)pred_f;
    const v4i* __restrict__ m4 = (const v4i*)mask;

    u64 A1 = 0, A2 = 0, AN = 0;

    const int totalWaves = (int)(gridDim.x * blockDim.x) >> 6;
    const int gstride    = totalWaves * 256;   // float4 elems per unroll-group sweep

    if (n4 == gstride * GROUPS) {
        // Fast path: each wave owns contiguous 4KB chunks (256 float4), the
        // whole grid sweeps memory in lockstep (DRAM-row friendly).
        // Per-thread elems = GROUPS*16 = 128 < 256 -> single flush at end.
        const int W    = ((int)(blockIdx.x * blockDim.x) + tid) >> 6;
        const int lane = tid & 63;
        int base = W * 256 + lane;
        for (int g = 0; g < GROUPS; ++g, base += gstride) {
            // Issue all 8 loads (nt: streaming / no-allocate hint) ...
            v4f a0 = __builtin_nontemporal_load(p4 + base);
            v4f a1 = __builtin_nontemporal_load(p4 + base + 64);
            v4f a2 = __builtin_nontemporal_load(p4 + base + 128);
            v4f a3 = __builtin_nontemporal_load(p4 + base + 192);
            v4i b0 = __builtin_nontemporal_load(m4 + base);
            v4i b1 = __builtin_nontemporal_load(m4 + base + 64);
            v4i b2 = __builtin_nontemporal_load(m4 + base + 128);
            v4i b3 = __builtin_nontemporal_load(m4 + base + 192);
            // ... and forbid the scheduler from sinking any of them below here.
            __builtin_amdgcn_sched_barrier(0);
            accum4(a0, b0, A1, A2, AN);
            accum4(a1, b1, A1, A2, AN);
            accum4(a2, b2, A1, A2, AN);
            accum4(a3, b3, A1, A2, AN);
        }
        FLUSH();
    } else {
        // Generic path: plain grid-stride with periodic flush.
        const int nt = gridDim.x * blockDim.x;
        int i = blockIdx.x * blockDim.x + tid;
        int cin = 0;
        for (; i < n4; i += nt) {
            accum4(p4[i], m4[i], A1, A2, AN);
            cin += 4;
            if (cin >= 224) { FLUSH(); cin = 0; }
        }
        FLUSH();
        for (int j = (n4 << 2) + blockIdx.x * blockDim.x + tid; j < n; j += nt) {
            int p = (int)pred_f[j];
            int m = mask[j];
            #pragma unroll
            for (int c = 0; c < NC; ++c) {
                u32 a = (p == c), b = (m == c);
                den1[c] += a;
                den2[c] += b;
                num [c] += a & b;
            }
        }
    }

    // wave-level butterfly reduce (wave = 64 lanes)
    #pragma unroll
    for (int c = 0; c < NC; ++c) {
        #pragma unroll
        for (int off = 32; off > 0; off >>= 1) {
            den1[c] += __shfl_xor(den1[c], off, 64);
            den2[c] += __shfl_xor(den2[c], off, 64);
            num [c] += __shfl_xor(num [c], off, 64);
        }
    }

    __shared__ u32 s_cnt[3 * NC];
    if (tid < 3 * NC) s_cnt[tid] = 0;
    __syncthreads();

    if ((tid & 63) == 0) {
        #pragma unroll
        for (int c = 0; c < NC; ++c) {
            atomicAdd(&s_cnt[c],          den1[c]);
            atomicAdd(&s_cnt[NC + c],     den2[c]);
            atomicAdd(&s_cnt[2 * NC + c], num [c]);
        }
    }
    __syncthreads();

    if (tid < 3 * NC) {
        atomicAdd(&cnt[tid * 16], s_cnt[tid]);
    }
}

__global__ void dice_final_kernel(const u32* __restrict__ cnt,
                                  float* __restrict__ out)
{
    if (blockIdx.x == 0 && threadIdx.x == 0) {
        float s = 0.0f;
        #pragma unroll
        for (int c = 0; c < NC; ++c) {
            float d1 = (float)cnt[c * 16];
            float d2 = (float)cnt[(NC + c) * 16];
            float nm = (float)cnt[(2 * NC + c) * 16];
            s += 2.0f * ((nm + DICE_EPS) / (d1 + d2 + DICE_EPS));
        }
        out[0] = s / (float)NC;
    }
}

extern "C" void kernel_launch(void* const* d_in, const int* in_sizes, int n_in,
                              void* d_out, int out_size, void* d_ws, size_t ws_size,
                              hipStream_t stream) {
    const float* pred = (const float*)d_in[0];   // "output": float32 labels
    const int*   mask = (const int*)d_in[1];     // "mask": int32 labels
    const int n = in_sizes[0];                   // 128*512*512 = 33,554,432

    u32* cnt = (u32*)d_ws;
    hipMemsetAsync(d_ws, 0, 256 * sizeof(u32), stream);

    dice_hist_kernel<<<BLOCKS, 256, 0, stream>>>(pred, mask, cnt, n);
    dice_final_kernel<<<1, 64, 0, stream>>>(cnt, (float*)d_out);
}